// Round 1
// baseline (641.656 us; speedup 1.0000x reference)
//
#include <hip/hip_runtime.h>

#define T_SEQ 100
#define C_EMB 16
#define DCOL  256

// d_ws float layout:
//   [0, 256)        : M'[k][c]  = 0.25*log2(e) * sum_d WQ[k][d]*WK[c][d]   (16x16)
//   [256, 256+4096) : WV[c][j]  = sum_h Wv[c][h]*Wdv[h][j]                 (16x256)

__global__ __launch_bounds__(256) void prep_kernel(
    const float* __restrict__ Wk, const float* __restrict__ Wq,
    const float* __restrict__ Wv, const float* __restrict__ Wdk,
    const float* __restrict__ Wdq, const float* __restrict__ Wdv,
    float* __restrict__ ws)
{
    __shared__ float WQL[16][260];
    __shared__ float WKL[16][260];
    const int tid = threadIdx.x;   // 0..255, acts as output column d/j

    // WQ = Wq@Wdq, WK = Wk@Wdk   (both [16][256])
    for (int i = 0; i < 16; ++i) {
        float aq = 0.f, ak = 0.f;
        for (int h = 0; h < 64; ++h) {
            aq += Wq[i*64 + h] * Wdq[h*256 + tid];
            ak += Wk[i*64 + h] * Wdk[h*256 + tid];
        }
        WQL[i][tid >> 4 == 0 ? tid : tid] = aq;  // plain store below instead
        WQL[i][tid] = aq;
        WKL[i][tid] = ak;
    }
    __syncthreads();

    // M'[k][c] = scale * sum_d WQ[k][d]*WK[c][d]; one thread per element
    {
        const float scale = 0.25f * 1.4426950408889634f;  // C^-0.5 * log2(e)
        const int k = tid >> 4;
        const int c = tid & 15;
        float acc = 0.f;
        for (int d = 0; d < 256; ++d)
            acc += WQL[k][d] * WKL[c][d];
        ws[k*16 + c] = acc * scale;
    }

    // WV[c][j] = sum_h Wv[c][h]*Wdv[h][j]
    for (int c = 0; c < 16; ++c) {
        float acc = 0.f;
        for (int h = 0; h < 64; ++h)
            acc += Wv[c*64 + h] * Wdv[h*256 + tid];
        ws[256 + c*256 + tid] = acc;
    }
}

__global__ __launch_bounds__(128) void attn_kernel(
    const float* __restrict__ x, const float* __restrict__ ws,
    float* __restrict__ out)
{
    __shared__ float Zs[T_SEQ * 16];

    const int b   = blockIdx.x;
    const int tid = threadIdx.x;
    const int t   = tid;          // query row owned by this lane (valid if <100)
    const int wid = tid >> 6;     // wave id: 0 -> rows 0..63, 1 -> rows 64..99

    const float* __restrict__ xb = x + (size_t)b * (T_SEQ * C_EMB);

    // ---- Phase A: per-lane row: y = x_t @ M', then one-pass softmax*X ----
    const int tl = (t < T_SEQ) ? t : (T_SEQ - 1);  // clamp OOB lanes' loads
    float xt[16];
    {
        const float4* xr = (const float4*)(xb + tl * 16);
        #pragma unroll
        for (int i = 0; i < 4; ++i) {
            float4 q = xr[i];
            xt[4*i+0] = q.x; xt[4*i+1] = q.y; xt[4*i+2] = q.z; xt[4*i+3] = q.w;
        }
    }

    float y[16];
    #pragma unroll
    for (int c = 0; c < 16; ++c) y[c] = 0.f;
    #pragma unroll
    for (int k = 0; k < 16; ++k) {
        const float xk = xt[k];
        #pragma unroll
        for (int c = 0; c < 16; ++c)
            y[c] += xk * ws[k*16 + c];     // uniform address -> scalar load
    }

    float z[16];
    #pragma unroll
    for (int c = 0; c < 16; ++c) z[c] = 0.f;
    float l = 0.f;

    const int smax = (wid == 0) ? 64 : T_SEQ;  // wave-uniform trip count
    for (int s = 0; s < smax; ++s) {
        float sx[16];
        {
            const float4* xr = (const float4*)(xb + s * 16);  // wave-uniform addr
            #pragma unroll
            for (int i = 0; i < 4; ++i) {
                float4 q = xr[i];
                sx[4*i+0] = q.x; sx[4*i+1] = q.y; sx[4*i+2] = q.z; sx[4*i+3] = q.w;
            }
        }
        float sc = 0.f;
        #pragma unroll
        for (int c = 0; c < 16; ++c) sc += y[c] * sx[c];
        // scores bounded well under exp2 overflow; max-subtraction unnecessary
        float p = __builtin_amdgcn_exp2f(sc);
        p = (s <= t) ? p : 0.f;   // causal mask
        l += p;
        #pragma unroll
        for (int c = 0; c < 16; ++c) z[c] += p * sx[c];
    }

    if (t < T_SEQ) {
        const float li = __builtin_amdgcn_rcpf(l);
        #pragma unroll
        for (int i = 0; i < 4; ++i) {
            float4 q;
            q.x = z[4*i+0] * li; q.y = z[4*i+1] * li;
            q.z = z[4*i+2] * li; q.w = z[4*i+3] * li;
            ((float4*)&Zs[t * 16])[i] = q;
        }
    }
    __syncthreads();

    // ---- Phase C: out[t][:] = z[t] @ WV, lane j covers cols j+64g ----
    const int j = tid & 63;
    const float* __restrict__ WVp = ws + 256;
    float wv[16][4];
    #pragma unroll
    for (int c = 0; c < 16; ++c)
        #pragma unroll
        for (int g = 0; g < 4; ++g)
            wv[c][g] = WVp[c*256 + g*64 + j];

    float* __restrict__ outb = out + (size_t)b * (T_SEQ * DCOL);
    for (int tt = wid; tt < T_SEQ; tt += 2) {
        float zr[16];
        #pragma unroll
        for (int i = 0; i < 4; ++i) {
            float4 q = ((const float4*)&Zs[tt * 16])[i];   // LDS broadcast
            zr[4*i+0] = q.x; zr[4*i+1] = q.y; zr[4*i+2] = q.z; zr[4*i+3] = q.w;
        }
        float acc[4] = {0.f, 0.f, 0.f, 0.f};
        #pragma unroll
        for (int c = 0; c < 16; ++c)
            #pragma unroll
            for (int g = 0; g < 4; ++g)
                acc[g] += zr[c] * wv[c][g];
        #pragma unroll
        for (int g = 0; g < 4; ++g)
            outb[tt*256 + g*64 + j] = acc[g];  // 256B coalesced per instr
    }
}

extern "C" void kernel_launch(void* const* d_in, const int* in_sizes, int n_in,
                              void* d_out, int out_size, void* d_ws, size_t ws_size,
                              hipStream_t stream) {
    const float* x   = (const float*)d_in[0];
    const float* Wk  = (const float*)d_in[1];
    const float* Wq  = (const float*)d_in[2];
    const float* Wv  = (const float*)d_in[3];
    const float* Wdk = (const float*)d_in[4];
    const float* Wdq = (const float*)d_in[5];
    const float* Wdv = (const float*)d_in[6];
    float* out = (float*)d_out;
    float* ws  = (float*)d_ws;

    const int B = in_sizes[0] / (T_SEQ * C_EMB);

    prep_kernel<<<1, 256, 0, stream>>>(Wk, Wq, Wv, Wdk, Wdq, Wdv, ws);
    attn_kernel<<<B, 128, 0, stream>>>(x, ws, out);
}

// Round 2
// 563.067 us; speedup vs baseline: 1.1396x; 1.1396x over previous
//
#include <hip/hip_runtime.h>

#define T_SEQ 100
#define C_EMB 16
#define DCOL  256

// d_ws float layout:
//   [0, 256)        : M'[k][c] = 0.25*log2(e) * sum_d WQ[k][d]*WK[c][d]  (16x16)
//   [256, 256+4096) : WV[c][j] = sum_h Wv[c][h]*Wdv[h][j]                (16x256)

__global__ __launch_bounds__(256) void prep_kernel(
    const float* __restrict__ Wk, const float* __restrict__ Wq,
    const float* __restrict__ Wv, const float* __restrict__ Wdk,
    const float* __restrict__ Wdq, const float* __restrict__ Wdv,
    float* __restrict__ ws)
{
    __shared__ float WQL[16][260];   // padded; rows 1040B apart (16B-aligned)
    __shared__ float WKL[16][260];
    const int tid = threadIdx.x;     // output column d / j (0..255)

    // WQ = Wq@Wdq, WK = Wk@Wdk, WV = Wv@Wdv — register-accumulated over h.
    float aq[16], ak[16], av[16];
    #pragma unroll
    for (int i = 0; i < 16; ++i) { aq[i] = 0.f; ak[i] = 0.f; av[i] = 0.f; }
    for (int h = 0; h < 64; ++h) {
        const float wdq = Wdq[h*256 + tid];   // coalesced
        const float wdk = Wdk[h*256 + tid];
        const float wdv = Wdv[h*256 + tid];
        #pragma unroll
        for (int i = 0; i < 16; ++i) {
            aq[i] += Wq[i*64 + h] * wdq;      // uniform scalar operands
            ak[i] += Wk[i*64 + h] * wdk;
            av[i] += Wv[i*64 + h] * wdv;
        }
    }
    #pragma unroll
    for (int i = 0; i < 16; ++i) {
        WQL[i][tid] = aq[i];
        WKL[i][tid] = ak[i];
        ws[256 + i*256 + tid] = av[i];        // WV out
    }
    __syncthreads();

    // M'[k][c] = scale * sum_d WQ[k][d]*WK[c][d]; one thread per element.
    {
        const float scale = 0.25f * 1.4426950408889634f;  // C^-0.5 * log2(e)
        const int k = tid >> 4;
        const int c = tid & 15;
        float acc = 0.f;
        for (int d4 = 0; d4 < 64; ++d4) {
            float4 a = *(const float4*)&WQL[k][4*d4];
            float4 b = *(const float4*)&WKL[c][4*d4];
            acc += a.x*b.x + a.y*b.y + a.z*b.z + a.w*b.w;
        }
        ws[k*16 + c] = acc * scale;
    }
}

__global__ __launch_bounds__(128) void attn_kernel(
    const float* __restrict__ x, const float* __restrict__ ws,
    float* __restrict__ out)
{
    __shared__ float Xs[T_SEQ * 16];   // this block's x tile (6.4 KB)
    __shared__ float Zs[T_SEQ * 16];   // softmax-weighted x (6.4 KB)

    const int b   = blockIdx.x;
    const int tid = threadIdx.x;
    const int t   = tid;            // query row owned by this lane (valid if <100)
    const int wid = tid >> 6;       // wave 0 -> rows 0..63, wave 1 -> rows 64..99

    const float* __restrict__ xb = x + (size_t)b * (T_SEQ * C_EMB);

    // ---- stage x into LDS (400 float4s, coalesced) ----
    for (int i = tid; i < T_SEQ * 4; i += 128)
        ((float4*)Xs)[i] = ((const float4*)xb)[i];
    __syncthreads();

    // ---- Phase A: y = x_t @ M', then one-pass softmax*X ----
    const int tl = (t < T_SEQ) ? t : (T_SEQ - 1);
    float xt[16];
    #pragma unroll
    for (int i = 0; i < 4; ++i) {
        float4 q = ((const float4*)&Xs[tl * 16])[i];
        xt[4*i+0] = q.x; xt[4*i+1] = q.y; xt[4*i+2] = q.z; xt[4*i+3] = q.w;
    }

    float y[16];
    #pragma unroll
    for (int c = 0; c < 16; ++c) y[c] = 0.f;
    #pragma unroll
    for (int k = 0; k < 16; ++k) {
        const float xk = xt[k];
        #pragma unroll
        for (int c = 0; c < 16; ++c)
            y[c] += xk * ws[k*16 + c];        // uniform address -> scalar load
    }

    float z[16];
    #pragma unroll
    for (int c = 0; c < 16; ++c) z[c] = 0.f;
    float l = 0.f;

    const int smax = (wid == 0) ? 64 : T_SEQ;  // wave-uniform trip count
    for (int s = 0; s < smax; ++s) {
        float sx[16];
        #pragma unroll
        for (int i = 0; i < 4; ++i) {
            float4 q = ((const float4*)&Xs[s * 16])[i];  // LDS broadcast
            sx[4*i+0] = q.x; sx[4*i+1] = q.y; sx[4*i+2] = q.z; sx[4*i+3] = q.w;
        }
        float sc = 0.f;
        #pragma unroll
        for (int c = 0; c < 16; ++c) sc += y[c] * sx[c];
        // scores far below exp2 overflow; softmax shift-invariance makes
        // max-subtraction unnecessary in fp32
        float p = __builtin_amdgcn_exp2f(sc);
        p = (s <= t) ? p : 0.f;               // causal mask
        l += p;
        #pragma unroll
        for (int c = 0; c < 16; ++c) z[c] += p * sx[c];
    }

    if (t < T_SEQ) {
        const float li = __builtin_amdgcn_rcpf(l);
        #pragma unroll
        for (int i = 0; i < 4; ++i) {
            float4 q;
            q.x = z[4*i+0] * li; q.y = z[4*i+1] * li;
            q.z = z[4*i+2] * li; q.w = z[4*i+3] * li;
            ((float4*)&Zs[t * 16])[i] = q;
        }
    }
    __syncthreads();

    // ---- Phase C: out[t][4j..4j+3] = z[t] @ WV[:, 4j..4j+3] ----
    const int j = tid & 63;
    const float* __restrict__ WVp = ws + 256;
    float4 wv[16];
    #pragma unroll
    for (int c = 0; c < 16; ++c)
        wv[c] = *(const float4*)&WVp[c*256 + 4*j];   // 1 KB/wave, coalesced

    float* __restrict__ outb = out + (size_t)b * (T_SEQ * DCOL);
    for (int tt = wid; tt < T_SEQ; tt += 2) {
        float zr[16];
        #pragma unroll
        for (int i = 0; i < 4; ++i) {
            float4 q = ((const float4*)&Zs[tt * 16])[i];  // LDS broadcast
            zr[4*i+0] = q.x; zr[4*i+1] = q.y; zr[4*i+2] = q.z; zr[4*i+3] = q.w;
        }
        float4 acc = make_float4(0.f, 0.f, 0.f, 0.f);
        #pragma unroll
        for (int c = 0; c < 16; ++c) {
            acc.x += zr[c] * wv[c].x;
            acc.y += zr[c] * wv[c].y;
            acc.z += zr[c] * wv[c].z;
            acc.w += zr[c] * wv[c].w;
        }
        *(float4*)&outb[tt*256 + 4*j] = acc;   // global_store_dwordx4, 1 KB/wave
    }
}

extern "C" void kernel_launch(void* const* d_in, const int* in_sizes, int n_in,
                              void* d_out, int out_size, void* d_ws, size_t ws_size,
                              hipStream_t stream) {
    const float* x   = (const float*)d_in[0];
    const float* Wk  = (const float*)d_in[1];
    const float* Wq  = (const float*)d_in[2];
    const float* Wv  = (const float*)d_in[3];
    const float* Wdk = (const float*)d_in[4];
    const float* Wdq = (const float*)d_in[5];
    const float* Wdv = (const float*)d_in[6];
    float* out = (float*)d_out;
    float* ws  = (float*)d_ws;

    const int B = in_sizes[0] / (T_SEQ * C_EMB);

    prep_kernel<<<1, 256, 0, stream>>>(Wk, Wq, Wv, Wdk, Wdq, Wdv, ws);
    attn_kernel<<<B, 128, 0, stream>>>(x, ws, out);
}